// Round 2
// baseline (322.857 us; speedup 1.0000x reference)
//
#include <hip/hip_runtime.h>
#include <cmath>

// GCN 2-layer forward for MI355X.
// out = D^-1/2 (A+I) D^-1/2 (X W) + b, twice, relu between.
// R2: CSR gather. R4: g bf16. R5: MFMA split-bf16 GEMM. R6-R8: bucketed CSR build.
// R9: XCD slicing FAILED. R10: scalar-addressed gather. R11: bf16 h2, 2-MFMA gemm2.
// R12: LDS-fused gather+gemm2 FAILED. R13: predicated unroll-8 gather (tail kill).
// R14: dinv deferred out of layer-1 GEMM; merged csr+gemm1 launch; CHUNK 2048.
// R15: window-broadcast gathers (half-wave 128F / quarter-wave 64F, 8B lanes),
//      setup merged into scatter. Only +3us -> gathers are BYTES-bound, not
//      VMEM-issue bound.
// R16: degree-sorted node permutation. CSR blocks counting-sort nodes into
//      per-degree-class slack regions (host-computed Poisson caps + catch-all,
//      holes=0xFFFF). Gathers walk perm -> nodes in a wave have equal degree
//      -> degmax==deg; unroll granule 8->4. Kills the ~1.4x/1.5x clamped-lane
//      row-load waste (clamped lanes issued REAL duplicate loads).

constexpr int KD = 128;      // inner dim of both GEMMs (Fin = Fh = 128)
constexpr int CHUNK = 2048;  // edges per block in scatter pass
constexpr int BCAP = 6144;   // slack capacity per bucket (mean 4096, sigma ~64)
constexpr int NDEG = 48;     // degree classes 0..47, class 48 = catch-all

struct DegCaps { int base[NDEG + 1]; int cap[NDEG]; };

using short8  = __attribute__((ext_vector_type(8))) short;
using float4v = __attribute__((ext_vector_type(4))) float;

// ---------------- bf16 helpers (storage = ushort, math = fp32) ----------------

__device__ __forceinline__ unsigned short f2bf(float f) {
    unsigned int u = __float_as_uint(f);
    u = (u + 0x7fffu + ((u >> 16) & 1u)) >> 16;  // round-to-nearest-even
    return (unsigned short)u;
}

__device__ __forceinline__ float2 bfpair(unsigned int u) {
    float2 f;
    f.x = __uint_as_float(u << 16);          // low short = first feature
    f.y = __uint_as_float(u & 0xffff0000u);  // high short = second feature
    return f;
}

__device__ __forceinline__ unsigned int packbf(float x, float y) {
    return (unsigned int)f2bf(x) | ((unsigned int)f2bf(y) << 16);
}

// split x = hi + lo (both bf16); subtraction is exact, |err| ~ 2^-17 |x|
__device__ __forceinline__ void bfsplit(float x, unsigned short& h, unsigned short& l) {
    h = f2bf(x);
    float fh = __uint_as_float((unsigned int)h << 16);
    l = f2bf(x - fh);
}

// ------- MERGED: bucket_scatter (blocks [0,NBS)) + W transpose (rest) -------
// gcur must be zeroed (hipMemsetAsync) before this launch; counts zero-based.
__global__ __launch_bounds__(256) void scatter_setup(
        const int* __restrict__ row, const int* __restrict__ col,
        int* gcur, unsigned int* __restrict__ bpack, int E, int NBS,
        const float* __restrict__ W1, unsigned short* __restrict__ Wth1,
        unsigned short* __restrict__ Wtl1,
        const float* __restrict__ W2, unsigned short* __restrict__ Wth2,
        unsigned short* __restrict__ Wtl2) {
    __shared__ int lh[256];
    __shared__ int lbase[256];

    if ((int)blockIdx.x >= NBS) {
        // -------- weight transpose + split (96 blocks x 256 = 24576 elems) ----
        int id = ((int)blockIdx.x - NBS) * 256 + threadIdx.x;
        unsigned short h, l;
        if (id < 16384) {                    // W1: [128,128]
            int k = id >> 7, n = id & 127;
            bfsplit(W1[id], h, l);
            Wth1[n * KD + k] = h;
            Wtl1[n * KD + k] = l;
        } else {                             // W2: [128,64]
            int id2 = id - 16384;
            int k = id2 >> 6, n = id2 & 63;
            bfsplit(W2[id2], h, l);
            Wth2[n * KD + k] = h;
            Wtl2[n * KD + k] = l;
        }
        return;
    }

    // -------- edge scatter into slack buckets; record = (row<<16)|col --------
    lh[threadIdx.x] = 0;
    __syncthreads();
    int base = (int)blockIdx.x * CHUNK;
#pragma unroll
    for (int r = 0; r < CHUNK / 256; ++r) {
        int e = base + r * 256 + threadIdx.x;
        if (e < E) atomicAdd(&lh[col[e] >> 8], 1);
    }
    __syncthreads();
    int c0 = lh[threadIdx.x];
    lbase[threadIdx.x] = c0 ? (threadIdx.x * BCAP + atomicAdd(&gcur[threadIdx.x], c0)) : 0;
    __syncthreads();
    lh[threadIdx.x] = 0;  // reuse as local running offset
    __syncthreads();
#pragma unroll
    for (int r = 0; r < CHUNK / 256; ++r) {
        int e = base + r * 256 + threadIdx.x;
        if (e < E) {
            int c = col[e];
            int b = c >> 8;
            int slot = lbase[b] + atomicAdd(&lh[b], 1);
            bpack[slot] = ((unsigned int)row[e] << 16) | (unsigned int)c;
        }
    }
}

// ------- MERGED: bucket_csr (blocks [0,NBUCKET)) + layer-1 GEMM (rest) -------
// CSR blocks additionally counting-sort nodes by degree into perm (R16).
__global__ __launch_bounds__(256) void csr_and_gemm1(
        const unsigned int* __restrict__ bpack, const int* __restrict__ gcur,
        int* __restrict__ rowptr, float* __restrict__ dinv,
        unsigned short* __restrict__ srow, int N, int E, int NBUCKET,
        const float* __restrict__ X,
        const unsigned short* __restrict__ Wth,
        const unsigned short* __restrict__ Wtl,
        unsigned short* __restrict__ G,
        DegCaps dc, int* __restrict__ pcnt, unsigned short* __restrict__ perm) {
    __shared__ int s[256];
    __shared__ int lh[256];
    __shared__ int lcur[256];
    __shared__ int sh_bstart;

    if ((int)blockIdx.x < NBUCKET) {
        // ---------------- CSR build ----------------
        int b = blockIdx.x;
        int t = threadIdx.x;
        int cntb = gcur[t];          // zero-based count (R15)
        s[t] = cntb;
        __syncthreads();
        for (int off = 1; off < 256; off <<= 1) {
            int tv = (t >= off) ? s[t - off] : 0;
            __syncthreads();
            s[t] += tv;
            __syncthreads();
        }
        if (t == b) sh_bstart = s[t] - cntb;  // exclusive prefix of this bucket
        if (b == 0 && t == 0) rowptr[N] = E;
        lh[t] = 0;
        __syncthreads();
        int bstart = sh_bstart;
        int nE = gcur[b];
        int base = b * BCAP;
        for (int i = t; i < nE; i += 256)
            atomicAdd(&lh[bpack[base + i] & 255], 1);
        __syncthreads();
        int v = lh[t];
        s[t] = v;
        __syncthreads();
        for (int off = 1; off < 256; off <<= 1) {
            int tv = (t >= off) ? s[t - off] : 0;
            __syncthreads();
            s[t] += tv;
            __syncthreads();
        }
        int myStart = bstart + s[t] - v;  // exclusive
        int node = (b << 8) + t;
        if (node < N) {
            rowptr[node] = myStart;
            dinv[node] = rsqrtf(1.0f + (float)v);
            // ---- degree-class counting sort (R16) ----
            int slot;
            if (v < NDEG) {
                int off = atomicAdd(&pcnt[v], 1);
                slot = (off < dc.cap[v]) ? (dc.base[v] + off)
                                         : (dc.base[NDEG] + atomicAdd(&pcnt[NDEG], 1));
            } else {
                slot = dc.base[NDEG] + atomicAdd(&pcnt[NDEG], 1);
            }
            perm[slot] = (unsigned short)node;
        }
        lcur[t] = myStart;
        __syncthreads();
        for (int i = t; i < nE; i += 256) {
            unsigned int p = bpack[base + i];
            int slot = atomicAdd(&lcur[p & 255], 1);
            srow[slot] = (unsigned short)(p >> 16);
        }
    } else {
        // ---------------- layer-1 GEMM (split-A, 3 MFMAs, no dinv) ----------
        constexpr int FOUT = 128, NT = 8;
        int wave = threadIdx.x >> 6;
        int lane = threadIdx.x & 63;
        int row0 = (((int)blockIdx.x - NBUCKET) * 4 + wave) * 16;
        if (row0 >= N) return;
        int m = lane & 15;
        int quad = lane >> 4;

        float4v acc[NT];
#pragma unroll
        for (int ct = 0; ct < NT; ++ct) acc[ct] = (float4v){0.f, 0.f, 0.f, 0.f};

        const float* xrow = X + (size_t)(row0 + m) * KD + quad * 8;

#pragma unroll
        for (int ks = 0; ks < 4; ++ks) {
            float4 xa = *(const float4*)(xrow + ks * 32);
            float4 xb = *(const float4*)(xrow + ks * 32 + 4);
            float xs[8] = {xa.x, xa.y, xa.z, xa.w, xb.x, xb.y, xb.z, xb.w};
            short8 ah, al;
#pragma unroll
            for (int j = 0; j < 8; ++j) {
                unsigned short h, l;
                bfsplit(xs[j], h, l);
                ah[j] = (short)h;
                al[j] = (short)l;
            }
            int koff = ks * 32 + quad * 8;
#pragma unroll
            for (int ct = 0; ct < NT; ++ct) {
                short8 bh = *(const short8*)(Wth + (size_t)(ct * 16 + m) * KD + koff);
                short8 bl = *(const short8*)(Wtl + (size_t)(ct * 16 + m) * KD + koff);
                acc[ct] = __builtin_amdgcn_mfma_f32_16x16x32_bf16(ah, bh, acc[ct], 0, 0, 0);
                acc[ct] = __builtin_amdgcn_mfma_f32_16x16x32_bf16(al, bh, acc[ct], 0, 0, 0);
                acc[ct] = __builtin_amdgcn_mfma_f32_16x16x32_bf16(ah, bl, acc[ct], 0, 0, 0);
            }
        }

#pragma unroll
        for (int r = 0; r < 4; ++r) {
            int row = row0 + quad * 4 + r;
#pragma unroll
            for (int ct = 0; ct < NT; ++ct) {
                G[(size_t)row * FOUT + ct * 16 + m] = f2bf(acc[ct][r]);
            }
        }
    }
}

// -------- layer-2 GEMM (bf16 in): G = bf16(dinv*(H@W)), 2 MFMAs, no A-split --
__global__ __launch_bounds__(256) void gemm_mfma2(const unsigned short* __restrict__ H,
                                                  const unsigned short* __restrict__ Wth,
                                                  const unsigned short* __restrict__ Wtl,
                                                  const float* __restrict__ dinv,
                                                  unsigned short* __restrict__ G, int N) {
    constexpr int FOUT = 64, NT = 4;
    int wave = threadIdx.x >> 6;
    int lane = threadIdx.x & 63;
    int row0 = (blockIdx.x * 4 + wave) * 16;
    if (row0 >= N) return;
    int m = lane & 15;
    int quad = lane >> 4;

    float4v acc[NT];
#pragma unroll
    for (int ct = 0; ct < NT; ++ct) acc[ct] = (float4v){0.f, 0.f, 0.f, 0.f};

    const unsigned short* hrow = H + (size_t)(row0 + m) * KD + quad * 8;

#pragma unroll
    for (int ks = 0; ks < 4; ++ks) {
        short8 a = *(const short8*)(hrow + ks * 32);
        int koff = ks * 32 + quad * 8;
#pragma unroll
        for (int ct = 0; ct < NT; ++ct) {
            short8 bh = *(const short8*)(Wth + (size_t)(ct * 16 + m) * KD + koff);
            short8 bl = *(const short8*)(Wtl + (size_t)(ct * 16 + m) * KD + koff);
            acc[ct] = __builtin_amdgcn_mfma_f32_16x16x32_bf16(a, bh, acc[ct], 0, 0, 0);
            acc[ct] = __builtin_amdgcn_mfma_f32_16x16x32_bf16(a, bl, acc[ct], 0, 0, 0);
        }
    }

#pragma unroll
    for (int r = 0; r < 4; ++r) {
        int row = row0 + quad * 4 + r;
        float s = dinv[row];
#pragma unroll
        for (int ct = 0; ct < 4; ++ct) {
            G[(size_t)row * FOUT + ct * 16 + m] = f2bf(acc[ct][r] * s);
        }
    }
}

// ---------------- CSR gather + finalize (fused), bf16 operand ----------------
// F=128 (R16): half-wave per PERM SLOT; degree-sorted -> both halves have
// (near-)equal degree, degmax==deg. srow window (32 ids) + dinv loaded once
// per window, broadcast per-edge via __shfl; unroll granule 4.
template <bool RELU>
__global__ __launch_bounds__(256) void gather128(const unsigned short* __restrict__ perm,
                                                 const int* __restrict__ rowptr,
                                                 const unsigned short* __restrict__ srow,
                                                 const unsigned int* __restrict__ G,  // bf16x2
                                                 const float* __restrict__ dinv,
                                                 const float* __restrict__ bias,
                                                 unsigned int* __restrict__ H2,  // bf16x2 out
                                                 int N, int E, int CAPTOT) {
    int slot = (blockIdx.x * 256 + (int)threadIdx.x) >> 5;  // half-wave per slot
    int lane = threadIdx.x & 63;
    int l32 = lane & 31;
    int node = (slot < CAPTOT) ? (int)perm[slot] : 0xFFFF;
    bool valid = node < N;
    int nc = valid ? node : 0;   // clamped for safe addressing
    int beg = rowptr[nc];
    int end = rowptr[nc + 1];
    int deg = valid ? (end - beg) : 0;
    float dn = dinv[nc];

    // self-loop (x dinv[n]); row = 64 uints = 32 uint2
    uint2 s0 = ((const uint2*)G)[(size_t)nc * 32 + l32];
    float2 p0 = bfpair(s0.x), p1 = bfpair(s0.y);
    float ax = p0.x * dn, ay = p0.y * dn, az = p1.x * dn, aw = p1.y * dn;

    int degmax = max(deg, __shfl_xor(deg, 32));  // wave-uniform (==deg when sorted)

    for (int w = 0; w < degmax; w += 32) {
        // one lane-indexed load covers 32 edge row-ids for this half
        int li = w + l32;
        li = (li < deg) ? li : (deg > 0 ? deg - 1 : 0);
        li += beg;
        li = (li < E) ? li : (E - 1);
        int rv = (int)srow[li];
        float dv = dinv[rv];                   // pre-gather source dinv
        int lim = degmax - w;                  // uniform
        for (int g = 0; g < 32 && g < lim; g += 4) {
            uint2 u[4];
            float dr[4];
#pragma unroll
            for (int j = 0; j < 4; ++j) {
                int src = (lane & 32) | (g + j);    // broadcast within own half
                int r = __shfl(rv, src);
                dr[j] = __shfl(dv, src);
                u[j] = ((const uint2*)G)[(size_t)r * 32 + l32];
            }
            float sx = 0.f, sy = 0.f, sz = 0.f, sw = 0.f;
#pragma unroll
            for (int j = 0; j < 4; ++j) {
                bool ok = (w + g + j) < deg;
                unsigned int ux = ok ? u[j].x : 0u;
                unsigned int uy = ok ? u[j].y : 0u;
                float2 v0 = bfpair(ux), v1 = bfpair(uy);
                sx = fmaf(dr[j], v0.x, sx);
                sy = fmaf(dr[j], v0.y, sy);
                sz = fmaf(dr[j], v1.x, sz);
                sw = fmaf(dr[j], v1.y, sw);
            }
            ax += sx; ay += sy; az += sz; aw += sw;
        }
    }
    if (!valid) return;
    float4 bv = ((const float4*)bias)[l32];
    float ox = ax * dn + bv.x;
    float oy = ay * dn + bv.y;
    float oz = az * dn + bv.z;
    float ow = aw * dn + bv.w;
    if (RELU) {
        ox = fmaxf(ox, 0.f); oy = fmaxf(oy, 0.f);
        oz = fmaxf(oz, 0.f); ow = fmaxf(ow, 0.f);
    }
    unsigned long long pv =
        ((unsigned long long)packbf(oz, ow) << 32) | (unsigned long long)packbf(ox, oy);
    __builtin_nontemporal_store(pv, (unsigned long long*)H2 + (size_t)nc * 32 + l32);
}

// F=64 (R16): quarter-wave per perm slot (16 lanes x 8B = 128B row); sorted
// degrees -> dm==deg; unroll granule 4; g2 pre-scaled by source dinv.
template <bool RELU>
__global__ __launch_bounds__(256) void gather64(const unsigned short* __restrict__ perm,
                                                const int* __restrict__ rowptr,
                                                const unsigned short* __restrict__ srow,
                                                const unsigned int* __restrict__ G,  // bf16x2
                                                const float* __restrict__ dinv,
                                                const float* __restrict__ bias,
                                                float* __restrict__ O, int N, int E,
                                                int CAPTOT) {
    int slot = (blockIdx.x * 256 + (int)threadIdx.x) >> 4;  // quarter-wave per slot
    int lane = threadIdx.x & 63;
    int l16 = lane & 15;
    int node = (slot < CAPTOT) ? (int)perm[slot] : 0xFFFF;
    bool valid = node < N;
    int nc = valid ? node : 0;
    int beg = rowptr[nc];
    int end = rowptr[nc + 1];
    int deg = valid ? (end - beg) : 0;

    // self-loop; row = 32 uints = 16 uint2
    uint2 s0 = ((const uint2*)G)[(size_t)nc * 16 + l16];
    float2 p0 = bfpair(s0.x), p1 = bfpair(s0.y);
    float ax = p0.x, ay = p0.y, az = p1.x, aw = p1.y;

    int dm = max(deg, __shfl_xor(deg, 16));
    dm = max(dm, __shfl_xor(dm, 32));   // wave-uniform over 4 quarters

    for (int w = 0; w < dm; w += 16) {
        int li = w + l16;
        li = (li < deg) ? li : (deg > 0 ? deg - 1 : 0);
        li += beg;
        li = (li < E) ? li : (E - 1);
        int rv = (int)srow[li];
        int lim = dm - w;
        for (int g = 0; g < 16 && g < lim; g += 4) {
            uint2 u[4];
#pragma unroll
            for (int j = 0; j < 4; ++j) {
                int src = (lane & 48) | (g + j);    // broadcast within own quarter
                int r = __shfl(rv, src);
                u[j] = ((const uint2*)G)[(size_t)r * 16 + l16];
            }
            float sx = 0.f, sy = 0.f, sz = 0.f, sw = 0.f;
#pragma unroll
            for (int j = 0; j < 4; ++j) {
                bool ok = (w + g + j) < deg;
                unsigned int ux = ok ? u[j].x : 0u;
                unsigned int uy = ok ? u[j].y : 0u;
                float2 v0 = bfpair(ux), v1 = bfpair(uy);
                sx += v0.x; sy += v0.y; sz += v1.x; sw += v1.y;
            }
            ax += sx; ay += sy; az += sz; aw += sw;
        }
    }
    if (!valid) return;
    float s = dinv[nc];
    float4 bv = ((const float4*)bias)[l16];
    float ox = ax * s + bv.x;
    float oy = ay * s + bv.y;
    float oz = az * s + bv.z;
    float ow = aw * s + bv.w;
    if (RELU) {
        ox = fmaxf(ox, 0.f); oy = fmaxf(oy, 0.f);
        oz = fmaxf(oz, 0.f); ow = fmaxf(ow, 0.f);
    }
    float4v o = {ox, oy, oz, ow};
    __builtin_nontemporal_store(o, (float4v*)O + (size_t)nc * 16 + l16);
}

extern "C" void kernel_launch(void* const* d_in, const int* in_sizes, int n_in,
                              void* d_out, int out_size, void* d_ws, size_t ws_size,
                              hipStream_t stream) {
    const float* x  = (const float*)d_in[0];
    const int*   ei = (const int*)d_in[1];   // int32
    const float* W1 = (const float*)d_in[2];
    const float* b1 = (const float*)d_in[3];
    const float* W2 = (const float*)d_in[4];
    const float* b2 = (const float*)d_in[5];
    float* out = (float*)d_out;

    int N = in_sizes[0] / 128;
    int E = in_sizes[1] / 2;
    const int* row = ei;       // edge_index[0]
    const int* col = ei + E;   // edge_index[1]

    // Workspace layout (all regions written before read each call)
    char* ws = (char*)d_ws;
    float* dinv   = (float*)(ws + 0x000000);             // 200 KB
    int*   rowptr = (int*)  (ws + 0x080000);             // 200 KB + 4
    int*   gcur   = (int*)  (ws + 0x0F9000);             // 1 KB (+ pcnt 256B)
    int*   pcnt   = gcur + 256;                          // 49 ints
    unsigned short* srow = (unsigned short*)(ws + 0x100000);   // 1.6 MB
    unsigned short* perm = (unsigned short*)(ws + 0x300000);   // ~150 KB (R16)
    unsigned short* g1 = (unsigned short*)(ws + 0x440000);     // 12.8 MB
    unsigned short* wth1 = (unsigned short*)(ws + 0x10C0000);  // 32 KB
    unsigned short* wtl1 = (unsigned short*)(ws + 0x10D0000);  // 32 KB
    unsigned short* wth2 = (unsigned short*)(ws + 0x10E0000);  // 16 KB
    unsigned short* wtl2 = (unsigned short*)(ws + 0x10F0000);  // 16 KB
    unsigned short* h2 = (unsigned short*)(ws + 0x1200000);    // 12.8 MB (bf16)
    unsigned short* g2 = (unsigned short*)(ws + 0x2C00000);    // 6.4 MB
    // Packed slack bucket buffer (256 x BCAP uints = 6.29 MB) overlaps h2's
    // region: consumed by csr_and_gemm1 before gather128 first writes h2.
    unsigned int* bpack = (unsigned int*)(ws + 0x1200000);     // 6.29 MB

    // ---- degree-class capacities (Poisson(lam = E/N) + 5.5-sigma slack) ----
    DegCaps dc;
    double lam = (double)E / (double)N;
    double p = exp(-lam);
    int acc = 0;
    for (int d = 0; d < NDEG; ++d) {
        dc.base[d] = acc;
        dc.cap[d] = (int)((double)N * p) + 384;
        acc += dc.cap[d];
        p *= lam / (double)(d + 1);
    }
    dc.base[NDEG] = acc;        // catch-all region
    int CAPTOT = acc + 4096;    // catch-all cap 4096 (deterministic input; ~0 used)

    int NB_BKT  = (E + CHUNK - 1) / CHUNK;   // 391
    int NBUCKET = (N + 255) / 256;           // 196
    int NB_GEMM1 = (N + 63) / 64;            // 782
    int NB_SETUP = 96;                       // 24576 transpose elems / 256

    // ---- counter zero + perm hole-fill + merged scatter/setup + CSR/GEMM1 ----
    hipMemsetAsync(gcur, 0, (256 + 64) * sizeof(int), stream);
    hipMemsetAsync(perm, 0xFF, (size_t)CAPTOT * sizeof(unsigned short), stream);
    scatter_setup<<<NB_BKT + NB_SETUP, 256, 0, stream>>>(
        row, col, gcur, bpack, E, NB_BKT, W1, wth1, wtl1, W2, wth2, wtl2);
    csr_and_gemm1<<<NBUCKET + NB_GEMM1, 256, 0, stream>>>(
        bpack, gcur, rowptr, dinv, srow, N, E, NBUCKET, x, wth1, wtl1, g1,
        dc, pcnt, perm);

    int nb;
    // ---- layer-1 gather (dinv folded in), half-wave per perm slot ----
    nb = (CAPTOT + 7) / 8;
    gather128<true><<<nb, 256, 0, stream>>>(perm, rowptr, srow,
                                            (const unsigned int*)g1,
                                            dinv, b1, (unsigned int*)h2, N, E, CAPTOT);

    // ---- layer 2 (F=64, no relu) ----
    nb = (N + 63) / 64;
    gemm_mfma2<<<nb, 256, 0, stream>>>(h2, wth2, wtl2, dinv, g2, N);
    nb = (CAPTOT + 15) / 16;   // quarter-wave per perm slot
    gather64<false><<<nb, 256, 0, stream>>>(perm, rowptr, srow,
                                            (const unsigned int*)g2,
                                            dinv, b2, out, N, E, CAPTOT);
}

// Round 3
// 182.633 us; speedup vs baseline: 1.7678x; 1.7678x over previous
//
#include <hip/hip_runtime.h>

// GCN 2-layer forward for MI355X.
// out = D^-1/2 (A+I) D^-1/2 (X W) + b, twice, relu between.
// R2: CSR gather. R4: g bf16. R5: MFMA split-bf16 GEMM. R6-R8: bucketed CSR build.
// R9: XCD slicing FAILED. R10: scalar-addressed gather. R11: bf16 h2, 2-MFMA gemm2.
// R12: LDS-fused gather+gemm2 FAILED (8-node block, MFMA tile mismatch).
// R13: predicated unroll-8 gather. R14: dinv deferred; merged csr+gemm1 launch.
// R15: window-broadcast gathers (issue-rate halved) -> +3us NULL: gathers are
//      NOT VMEM-issue bound.
// R16: degree-sorted perm via global-atomic counting sort -> csr_and_gemm1
//      162us (atomic serialization, 50k same-line device atomics); gathers
//      unchanged -> NOT imbalance-bound either (clamped dup loads are L1-free).
//      REVERTED.
// R17: quarter-wave (16 lanes x 16B) gather128 -> block = 16 nodes = one MFMA
//      row-tile; gemm2 FUSED into its epilogue via 4KB LDS h-tile (bit-identical
//      MFMA sequence to gemm_mfma2). Deletes gemm2 launch + h2 buffer
//      (25.6MB round-trip). gather64 = R15 verbatim.

constexpr int KD = 128;      // inner dim of both GEMMs (Fin = Fh = 128)
constexpr int CHUNK = 2048;  // edges per block in scatter pass
constexpr int BCAP = 6144;   // slack capacity per bucket (mean 4096, sigma ~64)

using short8  = __attribute__((ext_vector_type(8))) short;
using float4v = __attribute__((ext_vector_type(4))) float;
using uint4v  = __attribute__((ext_vector_type(4))) unsigned int;

// ---------------- bf16 helpers (storage = ushort, math = fp32) ----------------

__device__ __forceinline__ unsigned short f2bf(float f) {
    unsigned int u = __float_as_uint(f);
    u = (u + 0x7fffu + ((u >> 16) & 1u)) >> 16;  // round-to-nearest-even
    return (unsigned short)u;
}

__device__ __forceinline__ float2 bfpair(unsigned int u) {
    float2 f;
    f.x = __uint_as_float(u << 16);          // low short = first feature
    f.y = __uint_as_float(u & 0xffff0000u);  // high short = second feature
    return f;
}

__device__ __forceinline__ unsigned int packbf(float x, float y) {
    return (unsigned int)f2bf(x) | ((unsigned int)f2bf(y) << 16);
}

// split x = hi + lo (both bf16); subtraction is exact, |err| ~ 2^-17 |x|
__device__ __forceinline__ void bfsplit(float x, unsigned short& h, unsigned short& l) {
    h = f2bf(x);
    float fh = __uint_as_float((unsigned int)h << 16);
    l = f2bf(x - fh);
}

// ------- MERGED: bucket_scatter (blocks [0,NBS)) + W transpose (rest) -------
// gcur must be zeroed (hipMemsetAsync) before this launch; counts zero-based.
__global__ __launch_bounds__(256) void scatter_setup(
        const int* __restrict__ row, const int* __restrict__ col,
        int* gcur, unsigned int* __restrict__ bpack, int E, int NBS,
        const float* __restrict__ W1, unsigned short* __restrict__ Wth1,
        unsigned short* __restrict__ Wtl1,
        const float* __restrict__ W2, unsigned short* __restrict__ Wth2,
        unsigned short* __restrict__ Wtl2) {
    __shared__ int lh[256];
    __shared__ int lbase[256];

    if ((int)blockIdx.x >= NBS) {
        // -------- weight transpose + split (96 blocks x 256 = 24576 elems) ----
        int id = ((int)blockIdx.x - NBS) * 256 + threadIdx.x;
        unsigned short h, l;
        if (id < 16384) {                    // W1: [128,128]
            int k = id >> 7, n = id & 127;
            bfsplit(W1[id], h, l);
            Wth1[n * KD + k] = h;
            Wtl1[n * KD + k] = l;
        } else {                             // W2: [128,64]
            int id2 = id - 16384;
            int k = id2 >> 6, n = id2 & 63;
            bfsplit(W2[id2], h, l);
            Wth2[n * KD + k] = h;
            Wtl2[n * KD + k] = l;
        }
        return;
    }

    // -------- edge scatter into slack buckets; record = (row<<16)|col --------
    lh[threadIdx.x] = 0;
    __syncthreads();
    int base = (int)blockIdx.x * CHUNK;
#pragma unroll
    for (int r = 0; r < CHUNK / 256; ++r) {
        int e = base + r * 256 + threadIdx.x;
        if (e < E) atomicAdd(&lh[col[e] >> 8], 1);
    }
    __syncthreads();
    int c0 = lh[threadIdx.x];
    lbase[threadIdx.x] = c0 ? (threadIdx.x * BCAP + atomicAdd(&gcur[threadIdx.x], c0)) : 0;
    __syncthreads();
    lh[threadIdx.x] = 0;  // reuse as local running offset
    __syncthreads();
#pragma unroll
    for (int r = 0; r < CHUNK / 256; ++r) {
        int e = base + r * 256 + threadIdx.x;
        if (e < E) {
            int c = col[e];
            int b = c >> 8;
            int slot = lbase[b] + atomicAdd(&lh[b], 1);
            bpack[slot] = ((unsigned int)row[e] << 16) | (unsigned int)c;
        }
    }
}

// ------- MERGED: bucket_csr (blocks [0,NBUCKET)) + layer-1 GEMM (rest) -------
__global__ __launch_bounds__(256) void csr_and_gemm1(
        const unsigned int* __restrict__ bpack, const int* __restrict__ gcur,
        int* __restrict__ rowptr, float* __restrict__ dinv,
        unsigned short* __restrict__ srow, int N, int E, int NBUCKET,
        const float* __restrict__ X,
        const unsigned short* __restrict__ Wth,
        const unsigned short* __restrict__ Wtl,
        unsigned short* __restrict__ G) {
    __shared__ int s[256];
    __shared__ int lh[256];
    __shared__ int lcur[256];
    __shared__ int sh_bstart;

    if ((int)blockIdx.x < NBUCKET) {
        // ---------------- CSR build ----------------
        int b = blockIdx.x;
        int t = threadIdx.x;
        int cntb = gcur[t];          // zero-based count (R15)
        s[t] = cntb;
        __syncthreads();
        for (int off = 1; off < 256; off <<= 1) {
            int tv = (t >= off) ? s[t - off] : 0;
            __syncthreads();
            s[t] += tv;
            __syncthreads();
        }
        if (t == b) sh_bstart = s[t] - cntb;  // exclusive prefix of this bucket
        if (b == 0 && t == 0) rowptr[N] = E;
        lh[t] = 0;
        __syncthreads();
        int bstart = sh_bstart;
        int nE = gcur[b];
        int base = b * BCAP;
        for (int i = t; i < nE; i += 256)
            atomicAdd(&lh[bpack[base + i] & 255], 1);
        __syncthreads();
        int v = lh[t];
        s[t] = v;
        __syncthreads();
        for (int off = 1; off < 256; off <<= 1) {
            int tv = (t >= off) ? s[t - off] : 0;
            __syncthreads();
            s[t] += tv;
            __syncthreads();
        }
        int myStart = bstart + s[t] - v;  // exclusive
        int node = (b << 8) + t;
        if (node < N) {
            rowptr[node] = myStart;
            dinv[node] = rsqrtf(1.0f + (float)v);
        }
        lcur[t] = myStart;
        __syncthreads();
        for (int i = t; i < nE; i += 256) {
            unsigned int p = bpack[base + i];
            int slot = atomicAdd(&lcur[p & 255], 1);
            srow[slot] = (unsigned short)(p >> 16);
        }
    } else {
        // ---------------- layer-1 GEMM (split-A, 3 MFMAs, no dinv) ----------
        constexpr int FOUT = 128, NT = 8;
        int wave = threadIdx.x >> 6;
        int lane = threadIdx.x & 63;
        int row0 = (((int)blockIdx.x - NBUCKET) * 4 + wave) * 16;
        if (row0 >= N) return;
        int m = lane & 15;
        int quad = lane >> 4;

        float4v acc[NT];
#pragma unroll
        for (int ct = 0; ct < NT; ++ct) acc[ct] = (float4v){0.f, 0.f, 0.f, 0.f};

        const float* xrow = X + (size_t)(row0 + m) * KD + quad * 8;

#pragma unroll
        for (int ks = 0; ks < 4; ++ks) {
            float4 xa = *(const float4*)(xrow + ks * 32);
            float4 xb = *(const float4*)(xrow + ks * 32 + 4);
            float xs[8] = {xa.x, xa.y, xa.z, xa.w, xb.x, xb.y, xb.z, xb.w};
            short8 ah, al;
#pragma unroll
            for (int j = 0; j < 8; ++j) {
                unsigned short h, l;
                bfsplit(xs[j], h, l);
                ah[j] = (short)h;
                al[j] = (short)l;
            }
            int koff = ks * 32 + quad * 8;
#pragma unroll
            for (int ct = 0; ct < NT; ++ct) {
                short8 bh = *(const short8*)(Wth + (size_t)(ct * 16 + m) * KD + koff);
                short8 bl = *(const short8*)(Wtl + (size_t)(ct * 16 + m) * KD + koff);
                acc[ct] = __builtin_amdgcn_mfma_f32_16x16x32_bf16(ah, bh, acc[ct], 0, 0, 0);
                acc[ct] = __builtin_amdgcn_mfma_f32_16x16x32_bf16(al, bh, acc[ct], 0, 0, 0);
                acc[ct] = __builtin_amdgcn_mfma_f32_16x16x32_bf16(ah, bl, acc[ct], 0, 0, 0);
            }
        }

#pragma unroll
        for (int r = 0; r < 4; ++r) {
            int row = row0 + quad * 4 + r;
#pragma unroll
            for (int ct = 0; ct < NT; ++ct) {
                G[(size_t)row * FOUT + ct * 16 + m] = f2bf(acc[ct][r]);
            }
        }
    }
}

// ------------- FUSED: layer-1 gather + relu + layer-2 GEMM (R17) -------------
// Quarter-wave (16 lanes x dwordx4 = 256B row) per node; block = 256 thr =
// 16 nodes = one 16-row MFMA tile. Phase 1: CSR gather of g1 rows with
// window-broadcast srow/dinv (edges in groups of 4, same summation tree as the
// R16-validated granule-4 grouping). Epilogue packs h = relu(dinv*(sum)+b1) as
// bf16 into a 16x128 LDS tile. Phase 2 (after one barrier): wave w computes
// output cols [16w,16w+16) with the EXACT gemm_mfma2 sequence (bh/bl split,
// same ks order) and writes g2 = bf16(dinv*(H@W2)). h2 buffer eliminated.
__global__ __launch_bounds__(256) void gather128_gemm2(
        const int* __restrict__ rowptr,
        const unsigned short* __restrict__ srow,
        const unsigned int* __restrict__ G,      // g1 bf16x2
        const float* __restrict__ dinv,
        const float* __restrict__ bias,          // b1
        const unsigned short* __restrict__ Wth,  // wth2 (transposed, split hi)
        const unsigned short* __restrict__ Wtl,  // wtl2 (transposed, split lo)
        unsigned short* __restrict__ G2,         // g2 out (bf16, dinv-scaled)
        int N, int E) {
    __shared__ unsigned int lhs[16 * 64];  // 16 rows x 128 bf16 (packed pairs)
    __shared__ float ldinv[16];

    int lane = threadIdx.x & 63;
    int l16 = threadIdx.x & 15;
    int q = threadIdx.x >> 4;            // block-local node 0..15
    int node = (int)blockIdx.x * 16 + q;
    bool valid = node < N;
    int nc = valid ? node : 0;
    int beg = rowptr[nc];
    int end = rowptr[nc + 1];
    int deg = valid ? (end - beg) : 0;
    float dn = dinv[nc];
    if (l16 == 0) ldinv[q] = dn;

    const uint4v* Gv = (const uint4v*)G;  // row = 16 uint4

    // self-loop (x dinv[n]); lane covers features [l16*8, l16*8+8)
    uint4v s0 = Gv[(size_t)nc * 16 + l16];
    float ac[8];
    {
        float2 v0 = bfpair(s0[0]), v1 = bfpair(s0[1]);
        float2 v2 = bfpair(s0[2]), v3 = bfpair(s0[3]);
        ac[0] = v0.x * dn; ac[1] = v0.y * dn;
        ac[2] = v1.x * dn; ac[3] = v1.y * dn;
        ac[4] = v2.x * dn; ac[5] = v2.y * dn;
        ac[6] = v3.x * dn; ac[7] = v3.y * dn;
    }

    int dm = max(deg, __shfl_xor(deg, 16));
    dm = max(dm, __shfl_xor(dm, 32));    // wave-uniform over 4 quarters

    for (int w = 0; w < dm; w += 16) {
        // one lane-indexed load covers 16 edge row-ids for this quarter
        int li = w + l16;
        li = (li < deg) ? li : (deg > 0 ? deg - 1 : 0);
        li += beg;
        li = (li < E) ? li : (E - 1);
        int rv = (int)srow[li];
        float dv = dinv[rv];
        int lim = dm - w;                // uniform
        for (int g = 0; g < 16 && g < lim; g += 4) {
            uint4v u[4];
            float dr[4];
#pragma unroll
            for (int j = 0; j < 4; ++j) {
                int src = (lane & 48) | (g + j);   // broadcast within own quarter
                int r = __shfl(rv, src);
                dr[j] = __shfl(dv, src);
                u[j] = Gv[(size_t)r * 16 + l16];
            }
            float s[8] = {0.f, 0.f, 0.f, 0.f, 0.f, 0.f, 0.f, 0.f};
#pragma unroll
            for (int j = 0; j < 4; ++j) {
                bool ok = (w + g + j) < deg;
#pragma unroll
                for (int c = 0; c < 4; ++c) {
                    unsigned int uv = ok ? u[j][c] : 0u;
                    float2 v = bfpair(uv);
                    s[2 * c]     = fmaf(dr[j], v.x, s[2 * c]);
                    s[2 * c + 1] = fmaf(dr[j], v.y, s[2 * c + 1]);
                }
            }
#pragma unroll
            for (int c = 0; c < 8; ++c) ac[c] += s[c];
        }
    }

    // epilogue: h = relu(ac*dn + b1) -> bf16 pack into LDS tile
    {
        float4 bv0 = ((const float4*)bias)[l16 * 2];
        float4 bv1 = ((const float4*)bias)[l16 * 2 + 1];
        float o[8];
        o[0] = ac[0] * dn + bv0.x; o[1] = ac[1] * dn + bv0.y;
        o[2] = ac[2] * dn + bv0.z; o[3] = ac[3] * dn + bv0.w;
        o[4] = ac[4] * dn + bv1.x; o[5] = ac[5] * dn + bv1.y;
        o[6] = ac[6] * dn + bv1.z; o[7] = ac[7] * dn + bv1.w;
#pragma unroll
        for (int c = 0; c < 8; ++c) o[c] = fmaxf(o[c], 0.f);
        int lb = q * 64 + l16 * 4;
        lhs[lb + 0] = packbf(o[0], o[1]);
        lhs[lb + 1] = packbf(o[2], o[3]);
        lhs[lb + 2] = packbf(o[4], o[5]);
        lhs[lb + 3] = packbf(o[6], o[7]);
    }
    __syncthreads();

    // ---------------- fused gemm2: wave ct -> 16x16 output tile ----------------
    int ct = threadIdx.x >> 6;           // 0..3 -> cols [16ct, 16ct+16)
    int m = lane & 15;
    int quad = lane >> 4;

    float4v acc = (float4v){0.f, 0.f, 0.f, 0.f};
#pragma unroll
    for (int ks = 0; ks < 4; ++ks) {
        short8 a = *(const short8*)&lhs[m * 64 + ks * 16 + quad * 4];
        int koff = ks * 32 + quad * 8;
        short8 bh = *(const short8*)(Wth + (size_t)(ct * 16 + m) * KD + koff);
        short8 bl = *(const short8*)(Wtl + (size_t)(ct * 16 + m) * KD + koff);
        acc = __builtin_amdgcn_mfma_f32_16x16x32_bf16(a, bh, acc, 0, 0, 0);
        acc = __builtin_amdgcn_mfma_f32_16x16x32_bf16(a, bl, acc, 0, 0, 0);
    }

#pragma unroll
    for (int r = 0; r < 4; ++r) {
        int rr = quad * 4 + r;           // block-local output row
        int gnode = (int)blockIdx.x * 16 + rr;
        if (gnode < N) {
            G2[(size_t)gnode * 64 + ct * 16 + m] = f2bf(acc[r] * ldinv[rr]);
        }
    }
}

// F=64 (R15 verbatim): quarter-wave per node (16 lanes x 8B = 128B row) ->
// one row-load retires 4 edges. Window-broadcast; g2 pre-scaled by source
// dinv so no per-edge dinv needed. fp32 nt out.
template <bool RELU>
__global__ __launch_bounds__(256) void gather64(const int* __restrict__ rowptr,
                                                const unsigned short* __restrict__ srow,
                                                const unsigned int* __restrict__ G,  // bf16x2
                                                const float* __restrict__ dinv,
                                                const float* __restrict__ bias,
                                                float* __restrict__ O, int N, int E) {
    int tid = blockIdx.x * 256 + (int)threadIdx.x;
    int node = tid >> 4;          // quarter-wave per node
    int lane = threadIdx.x & 63;
    int l16 = lane & 15;
    bool valid = node < N;
    int nc = valid ? node : (N - 1);
    int beg = rowptr[nc];
    int end = rowptr[nc + 1];
    int deg = valid ? (end - beg) : 0;

    // self-loop; row = 32 uints = 16 uint2
    uint2 s0 = ((const uint2*)G)[(size_t)nc * 16 + l16];
    float2 p0 = bfpair(s0.x), p1 = bfpair(s0.y);
    float ax = p0.x, ay = p0.y, az = p1.x, aw = p1.y;

    int dm = max(deg, __shfl_xor(deg, 16));
    dm = max(dm, __shfl_xor(dm, 32));   // wave-uniform over 4 quarters

    for (int w = 0; w < dm; w += 16) {
        int li = w + l16;
        li = (li < deg) ? li : (deg > 0 ? deg - 1 : 0);
        li += beg;
        li = (li < E) ? li : (E - 1);
        int rv = (int)srow[li];
        int lim = dm - w;
        for (int g = 0; g < 16 && g < lim; g += 8) {
            uint2 u[8];
#pragma unroll
            for (int j = 0; j < 8; ++j) {
                int src = (lane & 48) | (g + j);    // broadcast within own quarter
                int r = __shfl(rv, src);
                u[j] = ((const uint2*)G)[(size_t)r * 16 + l16];
            }
            float sx = 0.f, sy = 0.f, sz = 0.f, sw = 0.f;
#pragma unroll
            for (int j = 0; j < 8; ++j) {
                bool ok = (w + g + j) < deg;
                unsigned int ux = ok ? u[j].x : 0u;
                unsigned int uy = ok ? u[j].y : 0u;
                float2 v0 = bfpair(ux), v1 = bfpair(uy);
                sx += v0.x; sy += v0.y; sz += v1.x; sw += v1.y;
            }
            ax += sx; ay += sy; az += sz; aw += sw;
        }
    }
    if (!valid) return;
    float s = dinv[nc];
    float4 bv = ((const float4*)bias)[l16];
    float ox = ax * s + bv.x;
    float oy = ay * s + bv.y;
    float oz = az * s + bv.z;
    float ow = aw * s + bv.w;
    if (RELU) {
        ox = fmaxf(ox, 0.f); oy = fmaxf(oy, 0.f);
        oz = fmaxf(oz, 0.f); ow = fmaxf(ow, 0.f);
    }
    float4v o = {ox, oy, oz, ow};
    __builtin_nontemporal_store(o, (float4v*)O + (size_t)nc * 16 + l16);
}

extern "C" void kernel_launch(void* const* d_in, const int* in_sizes, int n_in,
                              void* d_out, int out_size, void* d_ws, size_t ws_size,
                              hipStream_t stream) {
    const float* x  = (const float*)d_in[0];
    const int*   ei = (const int*)d_in[1];   // int32
    const float* W1 = (const float*)d_in[2];
    const float* b1 = (const float*)d_in[3];
    const float* W2 = (const float*)d_in[4];
    const float* b2 = (const float*)d_in[5];
    float* out = (float*)d_out;

    int N = in_sizes[0] / 128;
    int E = in_sizes[1] / 2;
    const int* row = ei;       // edge_index[0]
    const int* col = ei + E;   // edge_index[1]

    // Workspace layout (all regions written before read each call)
    char* ws = (char*)d_ws;
    float* dinv   = (float*)(ws + 0x000000);             // 200 KB
    int*   rowptr = (int*)  (ws + 0x080000);             // 200 KB + 4
    int*   gcur   = (int*)  (ws + 0x0F9000);             // 1 KB
    unsigned short* srow = (unsigned short*)(ws + 0x100000);   // 1.6 MB
    unsigned short* g1 = (unsigned short*)(ws + 0x440000);     // 12.8 MB
    unsigned short* wth1 = (unsigned short*)(ws + 0x10C0000);  // 32 KB
    unsigned short* wtl1 = (unsigned short*)(ws + 0x10D0000);  // 32 KB
    unsigned short* wth2 = (unsigned short*)(ws + 0x10E0000);  // 16 KB
    unsigned short* wtl2 = (unsigned short*)(ws + 0x10F0000);  // 16 KB
    // Packed slack bucket buffer (256 x BCAP uints = 6.29 MB); consumed by
    // csr_and_gemm1, dead afterwards (h2 eliminated in R17).
    unsigned int* bpack = (unsigned int*)(ws + 0x1200000);     // 6.29 MB
    unsigned short* g2 = (unsigned short*)(ws + 0x2C00000);    // 6.4 MB

    int NB_BKT  = (E + CHUNK - 1) / CHUNK;   // 391
    int NBUCKET = (N + 255) / 256;           // 196
    int NB_GEMM1 = (N + 63) / 64;            // 782
    int NB_SETUP = 96;                       // 24576 transpose elems / 256

    // ---- gcur zero + merged scatter/setup + merged CSR/GEMM1 ----
    hipMemsetAsync(gcur, 0, 256 * sizeof(int), stream);
    scatter_setup<<<NB_BKT + NB_SETUP, 256, 0, stream>>>(
        row, col, gcur, bpack, E, NB_BKT, W1, wth1, wtl1, W2, wth2, wtl2);
    csr_and_gemm1<<<NBUCKET + NB_GEMM1, 256, 0, stream>>>(
        bpack, gcur, rowptr, dinv, srow, N, E, NBUCKET, x, wth1, wtl1, g1);

    int nb;
    // ---- fused layer-1 gather + relu + layer-2 GEMM (16 nodes/block) ----
    nb = (N + 15) / 16;
    gather128_gemm2<<<nb, 256, 0, stream>>>(rowptr, srow, (const unsigned int*)g1,
                                            dinv, b1, wth2, wtl2, g2, N, E);

    // ---- layer-2 gather (quarter-wave per node) ----
    nb = (N + 15) / 16;
    gather64<false><<<nb, 256, 0, stream>>>(rowptr, srow, (const unsigned int*)g2,
                                            dinv, b2, out, N, E);
}